// Round 6
// baseline (1144.190 us; speedup 1.0000x reference)
//
#include <hip/hip_runtime.h>

typedef short frag  __attribute__((ext_vector_type(8)));
typedef float f32x4 __attribute__((ext_vector_type(4)));
typedef unsigned short u16;

#define E_TOT 1048576   // B*N*K
#define NK    524288    // N*K

// ws layout (bytes): wpk [0,348160); embn [348160,348672); bb16 [360448, +8388608)
#define WPK_US   174080
#define EMBN_OFF 348160
#define BB16_OFF 360448
#define WS_NEED  (BB16_OFF + 8388608)

__device__ __forceinline__ u16 f2bf(float f){
  unsigned int u = __float_as_uint(f);
  u += 0x7FFFu + ((u >> 16) & 1u);          // RNE
  return (u16)(u >> 16);
}
__device__ __forceinline__ unsigned cvtpk(float lo, float hi){
  unsigned r;
  asm("v_cvt_pk_bf16_f32 %0, %1, %2" : "=v"(r) : "v"(lo), "v"(hi));
  return r;
}
__device__ __forceinline__ float frcp(float x){ return __builtin_amdgcn_rcpf(x); }
__device__ __forceinline__ float vexp2(float x){          // 2^x, single v_exp_f32
  float r; asm("v_exp_f32 %0, %1" : "=v"(r) : "v"(x)); return r;
}
__device__ __forceinline__ float sigm(float y){
  return frcp(1.f + vexp2(-1.4426950408889634f * y));
}
__device__ __forceinline__ float gelu_f(float x){
  const float C1 = 2.0f * 0.7978845608028654f * 1.4426950408889634f;
  const float C2 = 0.044715f * C1;
  float z = x * fmaf(C2, x * x, C1);
  return x * frcp(1.f + vexp2(-z));
}

template<int N> struct IC { static constexpr int value = N; };

// ---------------- prep: pack weights, A-fragment layout with phi-permutation ----------------
__global__ void prep_kernel(const float* __restrict__ enc_w_in,
                            const float* __restrict__ enc_w_hid,
                            const float* __restrict__ enc_w_out,
                            const float* __restrict__ bias_w_in,
                            const float* __restrict__ bias_w_hid,
                            const float* __restrict__ bias_w_out,
                            const float* __restrict__ embed_table,
                            u16* __restrict__ wpk,
                            float* __restrict__ embn)
{
  int p = blockIdx.x * 256 + threadIdx.x;
  if (p < WPK_US) {
    const int base[12] = {0,16384,32768,49152,65536,81920,90112,106496,122880,139264,155648,172032};
    const int koff[12] = {0,128,0,0,0,0,0,128,0,0,0,0};
    const int njv[12]  = {128,128,128,128,128,64,128,128,128,128,128,1};
    const float* srcs[12] = {enc_w_in, enc_w_in, enc_w_hid, enc_w_hid+16384, enc_w_hid+32768,
                             enc_w_out, bias_w_in, bias_w_in, bias_w_hid, bias_w_hid+16384,
                             bias_w_hid+32768, bias_w_out};
    int L = 0;
    #pragma unroll
    for (int i = 1; i < 12; ++i) if (p >= base[i]) L = i;
    int r    = p - base[L];
    int f    = r >> 9;
    int lane = (r >> 3) & 63;
    int e    = r & 7;
    int s    = f & 3, t = f >> 2;
    int rho  = lane & 15, gf = lane >> 4;
    int nj   = njv[L];
    int j    = 16*t + 4*(((rho >> 2) ^ (t & 1)) & 3) + (rho & 3);
    int k    = 32*s + 8*gf + e + koff[L];
    wpk[p] = (j < nj) ? f2bf(srcs[L][k * nj + j]) : (u16)0;
  } else if (p < WPK_US + 128) {
    int q = p - WPK_US;
    int m = q >> 6;
    const float* row = embed_table + m * 64;
    float ss = 0.f;
    for (int t = 0; t < 64; ++t) { float v = row[t]; ss += v * v; }
    float nrm = fmaxf(sqrtf(ss), 1e-12f);
    embn[q] = row[q & 63] / nrm;
  }
}

// ---------------- prep: backbone f32 -> bf16 cache ----------------
__global__ void prep_backbone(const float* __restrict__ src, u16* __restrict__ dst)
{
  int i = (blockIdx.x * 256 + threadIdx.x) * 4;
  float4 v = *(const float4*)(src + i);
  unsigned lo = cvtpk(v.x, v.y), hi = cvtpk(v.z, v.w);
  *(uint2*)(dst + i) = make_uint2(lo, hi);
}

// ---------------- fused main kernel: barrier-free, zero LDS ----------------
template<bool BF>
__global__ __launch_bounds__(256, 3)
void fused_kernel(const float* __restrict__ backbone,
                  const u16*   __restrict__ bb16,
                  const float* __restrict__ ga,
                  const int*   __restrict__ idx,
                  const float* __restrict__ enc_b_in,
                  const float* __restrict__ enc_b_hid,
                  const float* __restrict__ enc_b_out,
                  const float* __restrict__ bias_b_in,
                  const float* __restrict__ bias_b_hid,
                  const float* __restrict__ bias_b_out,
                  const u16*   __restrict__ wpk,
                  const float* __restrict__ embn,
                  float* __restrict__ out)
{
  const int tid  = threadIdx.x;
  const int w    = tid >> 6;
  const int lane = tid & 63;
  const int g    = lane >> 4;
  const int li   = lane & 15;
  const int eW   = blockIdx.x * 128 + w * 32;   // wave owns 32 edges (2 tiles of 16)

  const int A0 = 4 * (li + 16 * ((((g & 1) << 1) | (g >> 1))));
  const int A2 = A0 ^ 64;

  // row indices (not byte offsets)
  int rxi[2], ryi[2];
  #pragma unroll
  for (int et = 0; et < 2; ++et) {
    int e  = eW + 16 * et + li;
    int b  = e >> 19;
    rxi[et] = (b << 14) + idx[E_TOT + e];
    ryi[et] = (b << 14) + idx[2 * E_TOT + e];
  }

  f32x4 acc[8][2];
  unsigned nb[2][4][4];
  const f32x4 kZ = {0.f, 0.f, 0.f, 0.f};

  union FU { unsigned u[4]; frag f; };

  auto getB_g = [&](const int* ri, int et, int s) -> frag {
    size_t off = (((size_t)(unsigned)ri[et]) << 7) + 32 * s + 8 * g;
    if constexpr (BF) {
      return *(const frag*)(bb16 + off);
    } else {
      const float* p = backbone + off;
      float4 lo = *(const float4*)p, hi = *(const float4*)(p + 4);
      FU fu;
      fu.u[0] = cvtpk(lo.x, lo.y); fu.u[1] = cvtpk(lo.z, lo.w);
      fu.u[2] = cvtpk(hi.x, hi.y); fu.u[3] = cvtpk(hi.z, hi.w);
      return fu.f;
    }
  };
  auto getBx = [&](int et, int s) -> frag { return getB_g(rxi, et, s); };
  auto getBy = [&](int et, int s) -> frag { return getB_g(ryi, et, s); };
  auto getBn = [&](int et, int s) -> frag {
    FU fu;
    fu.u[0] = nb[et][s][0]; fu.u[1] = nb[et][s][1];
    fu.u[2] = nb[et][s][2]; fu.u[3] = nb[et][s][3];
    return fu.f;
  };

  // A-frags straight from global (wpk is L2/L1-resident); ZF: first s-step uses C=0
  auto runLayer = [&](auto TC, auto ZFC, const u16* __restrict__ wp, auto getB){
    constexpr int T_ = decltype(TC)::value;
    constexpr bool ZF = (decltype(ZFC)::value != 0);
    #pragma unroll
    for (int s = 0; s < 4; ++s) {
      frag B0 = getB(0, s);
      frag B1 = getB(1, s);
      #pragma unroll
      for (int t = 0; t < T_; ++t) {
        frag A = *(const frag*)(wp + (t * 4 + s) * 512 + lane * 8);
        if (ZF && s == 0) {
          acc[t][0] = __builtin_amdgcn_mfma_f32_16x16x32_bf16(A, B0, kZ, 0, 0, 0);
          acc[t][1] = __builtin_amdgcn_mfma_f32_16x16x32_bf16(A, B1, kZ, 0, 0, 0);
        } else {
          acc[t][0] = __builtin_amdgcn_mfma_f32_16x16x32_bf16(A, B0, acc[t][0], 0, 0, 0);
          acc[t][1] = __builtin_amdgcn_mfma_f32_16x16x32_bf16(A, B1, acc[t][1], 0, 0, 0);
        }
      }
    }
  };

  // bias + act + in-register transpose, per sp-group to cap live regs
  auto finishLayer = [&](const float* bptr, bool gelu){
    #pragma unroll
    for (int sp = 0; sp < 4; ++sp) {
      unsigned pk0[2][2], pk1[2][2];             // [tt][et], t=2sp+tt
      #pragma unroll
      for (int tt = 0; tt < 2; ++tt) {
        int t = 2 * sp + tt;
        float4 bv = *(const float4*)(bptr + 16 * t + 4 * (g ^ (t & 1)));
        #pragma unroll
        for (int et = 0; et < 2; ++et) {
          float x0 = acc[t][et][0] + bv.x, x1 = acc[t][et][1] + bv.y;
          float x2 = acc[t][et][2] + bv.z, x3 = acc[t][et][3] + bv.w;
          if (gelu) { x0 = gelu_f(x0); x1 = gelu_f(x1); x2 = gelu_f(x2); x3 = gelu_f(x3); }
          else      { x0 = fmaxf(x0,0.f); x1 = fmaxf(x1,0.f); x2 = fmaxf(x2,0.f); x3 = fmaxf(x3,0.f); }
          pk0[tt][et] = cvtpk(x0, x1);
          pk1[tt][et] = cvtpk(x2, x3);
        }
      }
      #pragma unroll
      for (int et = 0; et < 2; ++et) {
        unsigned lo0 = pk0[0][et], hi0 = pk0[1][et];
        unsigned lo1 = pk1[0][et], hi1 = pk1[1][et];
        unsigned M0  = (g & 1) ? hi0 : lo0;
        unsigned M1  = (g & 1) ? hi1 : lo1;
        unsigned M0p = (g & 1) ? lo0 : hi0;
        unsigned M1p = (g & 1) ? lo1 : hi1;
        nb[et][sp][0] = (unsigned)__builtin_amdgcn_ds_bpermute(A0, (int)M0);
        nb[et][sp][1] = (unsigned)__builtin_amdgcn_ds_bpermute(A0, (int)M1);
        nb[et][sp][2] = (unsigned)__builtin_amdgcn_ds_bpermute(A2, (int)M0p);
        nb[et][sp][3] = (unsigned)__builtin_amdgcn_ds_bpermute(A2, (int)M1p);
      }
    }
  };

  // ================= ENC MLP =================
  runLayer(IC<8>{}, IC<1>{}, wpk + 0,      getBx);   // L1 x-half (C=0)
  runLayer(IC<8>{}, IC<0>{}, wpk + 16384,  getBy);   // L1 y-half (accumulate)
  finishLayer(enc_b_in, false);
  runLayer(IC<8>{}, IC<1>{}, wpk + 32768,  getBn);   // H1
  finishLayer(enc_b_hid + 0, false);
  runLayer(IC<8>{}, IC<1>{}, wpk + 49152,  getBn);   // H2
  finishLayer(enc_b_hid + 128, false);
  runLayer(IC<8>{}, IC<1>{}, wpk + 65536,  getBn);   // H3
  finishLayer(enc_b_hid + 256, false);
  runLayer(IC<4>{}, IC<1>{}, wpk + 81920,  getBn);   // ENC OUT (T=4)

  // ---- enc epilogue: bias add, L2-normalize, sigmoid dots ----
  float a0v[2], a1v[2];
  {
    #pragma unroll
    for (int t = 0; t < 4; ++t) {
      float4 bv = *(const float4*)(enc_b_out + 16 * t + 4 * (g ^ (t & 1)));
      #pragma unroll
      for (int et = 0; et < 2; ++et) {
        acc[t][et][0] += bv.x; acc[t][et][1] += bv.y;
        acc[t][et][2] += bv.z; acc[t][et][3] += bv.w;
      }
    }
    #pragma unroll
    for (int et = 0; et < 2; ++et) {
      float s2 = 0.f, p0 = 0.f, p1 = 0.f;
      #pragma unroll
      for (int t = 0; t < 4; ++t) {
        float4 em0 = *(const float4*)(embn + 16 * t + 4 * (g ^ (t & 1)));
        float4 em1 = *(const float4*)(embn + 64 + 16 * t + 4 * (g ^ (t & 1)));
        #pragma unroll
        for (int r = 0; r < 4; ++r) {
          float v = acc[t][et][r];
          float e0 = (r == 0) ? em0.x : (r == 1) ? em0.y : (r == 2) ? em0.z : em0.w;
          float e1 = (r == 0) ? em1.x : (r == 1) ? em1.y : (r == 2) ? em1.z : em1.w;
          s2 = fmaf(v, v, s2);
          p0 = fmaf(v, e0, p0);
          p1 = fmaf(v, e1, p1);
        }
      }
      s2 += __shfl_xor(s2, 16); s2 += __shfl_xor(s2, 32);
      p0 += __shfl_xor(p0, 16); p0 += __shfl_xor(p0, 32);
      p1 += __shfl_xor(p1, 16); p1 += __shfl_xor(p1, 32);
      float inv = frcp(fmaxf(sqrtf(s2), 1e-12f));
      a0v[et] = sigm(p0 * inv);
      a1v[et] = sigm(p1 * inv);
    }
  }

  // ================= BIAS MLP =================
  runLayer(IC<8>{}, IC<1>{}, wpk + 90112,  getBx);   // L1 x-half (C=0)
  runLayer(IC<8>{}, IC<0>{}, wpk + 106496, getBy);   // L1 y-half
  finishLayer(bias_b_in, true);
  runLayer(IC<8>{}, IC<1>{}, wpk + 122880, getBn);   // H1
  finishLayer(bias_b_hid + 0, true);
  runLayer(IC<8>{}, IC<1>{}, wpk + 139264, getBn);   // H2
  finishLayer(bias_b_hid + 128, true);
  runLayer(IC<8>{}, IC<1>{}, wpk + 155648, getBn);   // H3
  finishLayer(bias_b_hid + 256, true);
  runLayer(IC<1>{}, IC<1>{}, wpk + 172032, getBn);   // BIAS OUT (T=1)

  // ================= output =================
  if (g == 0) {
    float bb0 = bias_b_out[0];
    #pragma unroll
    for (int et = 0; et < 2; ++et) {
      int e   = eW + 16 * et + li;
      int b   = e >> 19;
      int off = e & (NK - 1);
      float g0 = ga[((size_t)b << 20) + off];
      float g1 = ga[((size_t)b << 20) + NK + off];
      float bi = acc[0][et][0] + bb0;
      out[e] = a0v[et] * (g0 - bi) + a1v[et] * (g1 - bi);
    }
  }
}

extern "C" void kernel_launch(void* const* d_in, const int* in_sizes, int n_in,
                              void* d_out, int out_size, void* d_ws, size_t ws_size,
                              hipStream_t stream) {
  const float* backbone   = (const float*)d_in[0];
  const float* ga         = (const float*)d_in[1];
  const float* embed      = (const float*)d_in[2];
  const float* enc_w_in   = (const float*)d_in[3];
  const float* enc_b_in   = (const float*)d_in[4];
  const float* enc_w_hid  = (const float*)d_in[5];
  const float* enc_b_hid  = (const float*)d_in[6];
  const float* enc_w_out  = (const float*)d_in[7];
  const float* enc_b_out  = (const float*)d_in[8];
  const float* bias_w_in  = (const float*)d_in[9];
  const float* bias_b_in  = (const float*)d_in[10];
  const float* bias_w_hid = (const float*)d_in[11];
  const float* bias_b_hid = (const float*)d_in[12];
  const float* bias_w_out = (const float*)d_in[13];
  const float* bias_b_out = (const float*)d_in[14];
  const int*   indices    = (const int*)d_in[15];

  u16*   wpk  = (u16*)d_ws;
  float* embn = (float*)((char*)d_ws + EMBN_OFF);
  u16*   bb16 = (u16*)((char*)d_ws + BB16_OFF);

  hipLaunchKernelGGL(prep_kernel, dim3(681), dim3(256), 0, stream,
                     enc_w_in, enc_w_hid, enc_w_out,
                     bias_w_in, bias_w_hid, bias_w_out,
                     embed, wpk, embn);

  bool bf = (ws_size >= (size_t)WS_NEED);
  if (bf) {
    hipLaunchKernelGGL(prep_backbone, dim3(4096), dim3(256), 0, stream, backbone, bb16);
    hipLaunchKernelGGL((fused_kernel<true>), dim3(8192), dim3(256), 0, stream,
                       backbone, bb16, ga, indices,
                       enc_b_in, enc_b_hid, enc_b_out,
                       bias_b_in, bias_b_hid, bias_b_out,
                       wpk, embn, (float*)d_out);
  } else {
    hipLaunchKernelGGL((fused_kernel<false>), dim3(8192), dim3(256), 0, stream,
                       backbone, bb16, ga, indices,
                       enc_b_in, enc_b_hid, enc_b_out,
                       bias_b_in, bias_b_hid, bias_b_out,
                       wpk, embn, (float*)d_out);
  }
}

// Round 7
// 612.625 us; speedup vs baseline: 1.8677x; 1.8677x over previous
//
#include <hip/hip_runtime.h>

typedef short frag   __attribute__((ext_vector_type(8)));
typedef float f32x4  __attribute__((ext_vector_type(4)));
typedef float f32x16 __attribute__((ext_vector_type(16)));
typedef unsigned short u16;

#define E_TOT 1048576   // B*N*K
#define NK    524288    // N*K

// ws layout (bytes): wpk [0,352256); embn [352256,352768); bb16 [352768, +8388608)
#define WPK_US   176128
#define EMBN_OFF 352256
#define BB16_OFF 352768
#define WS_NEED  (BB16_OFF + 8388608)

__device__ __forceinline__ u16 f2bf(float f){
  unsigned int u = __float_as_uint(f);
  u += 0x7FFFu + ((u >> 16) & 1u);          // RNE
  return (u16)(u >> 16);
}
__device__ __forceinline__ unsigned cvtpk(float lo, float hi){
  unsigned r;
  asm("v_cvt_pk_bf16_f32 %0, %1, %2" : "=v"(r) : "v"(lo), "v"(hi));
  return r;
}
// in-place: a = [a_lo, b_lo], b = [a_hi, b_hi]
__device__ __forceinline__ void plswap(unsigned &a, unsigned &b){
  asm("v_permlane32_swap_b32 %0, %1" : "+v"(a), "+v"(b));
}
__device__ __forceinline__ float frcp(float x){ return __builtin_amdgcn_rcpf(x); }
__device__ __forceinline__ float vexp2(float x){
  float r; asm("v_exp_f32 %0, %1" : "=v"(r) : "v"(x)); return r;
}
__device__ __forceinline__ float sigm(float y){
  return frcp(1.f + vexp2(-1.4426950408889634f * y));
}
__device__ __forceinline__ float gelu_f(float x){
  const float C1 = 2.0f * 0.7978845608028654f * 1.4426950408889634f;
  const float C2 = 0.044715f * C1;
  float z = x * fmaf(C2, x * x, C1);
  return x * frcp(1.f + vexp2(-z));
}

__device__ __forceinline__ void gl_lds16(const void* g, void* l){
#if __has_builtin(__builtin_amdgcn_global_load_lds)
  __builtin_amdgcn_global_load_lds(
      (const __attribute__((address_space(1))) unsigned int*)g,
      (__attribute__((address_space(3))) unsigned int*)l, 16, 0, 0);
#else
  *(uint4*)l = *(const uint4*)g;
#endif
}

template<int N> struct IC { static constexpr int value = N; };

// ---------------- prep: pack weights into 32x32x16 A-fragment layout ----------------
// chunk c, frag f = t*8+s, lane, elem e:  element = W[k][j],
//   j = 32t + (lane&31),  k = 16s + 8*(lane>>5) + e + koff[c]
__global__ void prep_kernel(const float* __restrict__ enc_w_in,
                            const float* __restrict__ enc_w_hid,
                            const float* __restrict__ enc_w_out,
                            const float* __restrict__ bias_w_in,
                            const float* __restrict__ bias_w_hid,
                            const float* __restrict__ bias_w_out,
                            const float* __restrict__ embed_table,
                            u16* __restrict__ wpk,
                            float* __restrict__ embn)
{
  int p = blockIdx.x * 256 + threadIdx.x;
  if (p < WPK_US) {
    const int base[12] = {0,16384,32768,49152,65536,81920,90112,106496,122880,139264,155648,172032};
    const int koff[12] = {0,128,0,0,0,0,0,128,0,0,0,0};
    const int njv[12]  = {128,128,128,128,128,64,128,128,128,128,128,1};
    const float* srcs[12] = {enc_w_in, enc_w_in, enc_w_hid, enc_w_hid+16384, enc_w_hid+32768,
                             enc_w_out, bias_w_in, bias_w_in, bias_w_hid, bias_w_hid+16384,
                             bias_w_hid+32768, bias_w_out};
    int L = 0;
    #pragma unroll
    for (int i = 1; i < 12; ++i) if (p >= base[i]) L = i;
    int r    = p - base[L];
    int f    = r >> 9;
    int q    = r & 511;
    int lane = q >> 3, e = q & 7;
    int t    = f >> 3, s = f & 7;
    int nj   = njv[L];
    int j    = 32*t + (lane & 31);
    int k    = 16*s + 8*(lane >> 5) + e + koff[L];
    wpk[p] = (j < nj) ? f2bf(srcs[L][k * nj + j]) : (u16)0;
  } else if (p < WPK_US + 128) {
    int q = p - WPK_US;
    int m = q >> 6;
    const float* row = embed_table + m * 64;
    float ss = 0.f;
    for (int t = 0; t < 64; ++t) { float v = row[t]; ss += v * v; }
    float nrm = fmaxf(sqrtf(ss), 1e-12f);
    embn[q] = row[q & 63] / nrm;
  }
}

// ---------------- prep: backbone f32 -> bf16 cache ----------------
__global__ void prep_backbone(const float* __restrict__ src, u16* __restrict__ dst)
{
  int i = (blockIdx.x * 256 + threadIdx.x) * 4;
  float4 v = *(const float4*)(src + i);
  unsigned lo = cvtpk(v.x, v.y), hi = cvtpk(v.z, v.w);
  *(uint2*)(dst + i) = make_uint2(lo, hi);
}

// ---------------- fused main kernel: r2 skeleton + 32x32x16 MFMA ----------------
template<bool BF>
__global__ __launch_bounds__(256, 3)
void fused_kernel(const float* __restrict__ backbone,
                  const u16*   __restrict__ bb16,
                  const float* __restrict__ ga,
                  const int*   __restrict__ idx,
                  const float* __restrict__ enc_b_in,
                  const float* __restrict__ enc_b_hid,
                  const float* __restrict__ enc_b_out,
                  const float* __restrict__ bias_b_in,
                  const float* __restrict__ bias_b_hid,
                  const float* __restrict__ bias_b_out,
                  const u16*   __restrict__ wpk,
                  const float* __restrict__ embn,
                  float* __restrict__ out)
{
  __shared__ __align__(16) u16 wbuf[16384];     // 32KB staged weights (one chunk)

  const int tid  = threadIdx.x;
  const int w    = tid >> 6;
  const int lane = tid & 63;
  const int h    = lane >> 5;          // k-half
  const int col  = lane & 31;          // edge within wave tile
  const int eW   = blockIdx.x * 128 + w * 32;   // wave owns 32 edges (one 32-col tile)
  const int e    = eW + col;

  auto stageW = [&](int base_us, int nfrag){
    for (int it = w; it < nfrag; it += 4)
      gl_lds16((const void*)(wpk + base_us + it * 512 + lane * 8),
               (void*)(&wbuf[it * 512]));
  };

  stageW(0, 32);                                 // enc L1x staged first

  // gather row indices (one edge per lane; halves share the edge)
  int b = e >> 19;
  int rxi = (b << 14) + idx[E_TOT + e];
  int ryi = (b << 14) + idx[2 * E_TOT + e];

  f32x16 acc[4];
  unsigned nb[8][4];                             // next-layer B-frags (8 k-steps)
  const f32x16 kZ = {0.f,0.f,0.f,0.f, 0.f,0.f,0.f,0.f, 0.f,0.f,0.f,0.f, 0.f,0.f,0.f,0.f};

  union FU { unsigned u[4]; frag f; };

  auto getB_g = [&](int ri, int s) -> frag {
    size_t off = (((size_t)(unsigned)ri) << 7) + 16 * s + 8 * h;
    if constexpr (BF) {
      return *(const frag*)(bb16 + off);
    } else {
      const float* p = backbone + off;
      float4 lo = *(const float4*)p, hi = *(const float4*)(p + 4);
      FU fu;
      fu.u[0] = cvtpk(lo.x, lo.y); fu.u[1] = cvtpk(lo.z, lo.w);
      fu.u[2] = cvtpk(hi.x, hi.y); fu.u[3] = cvtpk(hi.z, hi.w);
      return fu.f;
    }
  };
  auto getBx = [&](int s) -> frag { return getB_g(rxi, s); };
  auto getBy = [&](int s) -> frag { return getB_g(ryi, s); };
  auto getBn = [&](int s) -> frag {
    FU fu;
    fu.u[0] = nb[s][0]; fu.u[1] = nb[s][1];
    fu.u[2] = nb[s][2]; fu.u[3] = nb[s][3];
    return fu.f;
  };

  // S_ k-steps, T_ col-tiles; ZF: first step uses C=0 (no acc init needed)
  auto runLayer = [&](auto SC, auto TC, auto ZFC, auto getB){
    constexpr int S_ = decltype(SC)::value;
    constexpr int T_ = decltype(TC)::value;
    constexpr bool ZF = (decltype(ZFC)::value != 0);
    #pragma unroll
    for (int s = 0; s < S_; ++s) {
      frag B = getB(s);
      #pragma unroll
      for (int t = 0; t < T_; ++t) {
        frag A = *(const frag*)(&wbuf[(t * S_ + s) * 512 + lane * 8]);
        if (ZF && s == 0)
          acc[t] = __builtin_amdgcn_mfma_f32_32x32x16_bf16(A, B, kZ, 0, 0, 0);
        else
          acc[t] = __builtin_amdgcn_mfma_f32_32x32x16_bf16(A, B, acc[t], 0, 0, 0);
      }
    }
  };

  // bias + act + permlane transpose into nb (tile t -> k-steps 2t, 2t+1)
  auto finishLayer = [&](const float* bptr, bool gelu){
    #pragma unroll
    for (int t = 0; t < 4; ++t) {
      float x[16];
      #pragma unroll
      for (int q = 0; q < 4; ++q) {
        f32x4 bv = *(const f32x4*)(bptr + 32*t + 8*q + 4*h);
        #pragma unroll
        for (int i = 0; i < 4; ++i) x[4*q+i] = acc[t][4*q+i] + bv[i];
      }
      #pragma unroll
      for (int i = 0; i < 16; ++i)
        x[i] = gelu ? gelu_f(x[i]) : fmaxf(x[i], 0.f);
      unsigned wv[8];
      #pragma unroll
      for (int i = 0; i < 8; ++i) wv[i] = cvtpk(x[2*i], x[2*i+1]);
      plswap(wv[0], wv[2]); plswap(wv[1], wv[3]);
      plswap(wv[4], wv[6]); plswap(wv[5], wv[7]);
      nb[2*t][0] = wv[0]; nb[2*t][1] = wv[1]; nb[2*t][2] = wv[2]; nb[2*t][3] = wv[3];
      nb[2*t+1][0] = wv[4]; nb[2*t+1][1] = wv[5]; nb[2*t+1][2] = wv[6]; nb[2*t+1][3] = wv[7];
    }
  };

  // ================= ENC MLP =================
  __syncthreads();
  runLayer(IC<8>{}, IC<4>{}, IC<1>{}, getBx);    // L1 x-half (C=0)
  __syncthreads();
  stageW(16384, 32);                             // L1y
  __syncthreads();
  runLayer(IC<8>{}, IC<4>{}, IC<0>{}, getBy);    // L1 y-half (accumulate)
  __syncthreads();
  stageW(32768, 32);                             // H1
  finishLayer(enc_b_in, false);
  __syncthreads();
  runLayer(IC<8>{}, IC<4>{}, IC<1>{}, getBn);    // H1
  __syncthreads();
  stageW(49152, 32);                             // H2
  finishLayer(enc_b_hid + 0, false);
  __syncthreads();
  runLayer(IC<8>{}, IC<4>{}, IC<1>{}, getBn);    // H2
  __syncthreads();
  stageW(65536, 32);                             // H3
  finishLayer(enc_b_hid + 128, false);
  __syncthreads();
  runLayer(IC<8>{}, IC<4>{}, IC<1>{}, getBn);    // H3
  __syncthreads();
  stageW(81920, 16);                             // ENC OUT (T=2)
  finishLayer(enc_b_hid + 256, false);
  __syncthreads();
  runLayer(IC<8>{}, IC<2>{}, IC<1>{}, getBn);    // ENC OUT
  __syncthreads();
  stageW(90112, 32);                             // bias L1x (overlaps epilogue VALU)

  // ---- enc epilogue: bias add, L2-normalize, sigmoid dots ----
  float a0v, a1v;
  {
    float s2 = 0.f, p0 = 0.f, p1 = 0.f;
    #pragma unroll
    for (int t = 0; t < 2; ++t)
      #pragma unroll
      for (int q = 0; q < 4; ++q) {
        f32x4 bv = *(const f32x4*)(enc_b_out + 32*t + 8*q + 4*h);
        f32x4 e0 = *(const f32x4*)(embn + 32*t + 8*q + 4*h);
        f32x4 e1 = *(const f32x4*)(embn + 64 + 32*t + 8*q + 4*h);
        #pragma unroll
        for (int i = 0; i < 4; ++i) {
          float v = acc[t][4*q+i] + bv[i];
          s2 = fmaf(v, v, s2);
          p0 = fmaf(v, e0[i], p0);
          p1 = fmaf(v, e1[i], p1);
        }
      }
    s2 += __shfl_xor(s2, 32);
    p0 += __shfl_xor(p0, 32);
    p1 += __shfl_xor(p1, 32);
    float inv = frcp(fmaxf(sqrtf(s2), 1e-12f));
    a0v = sigm(p0 * inv);
    a1v = sigm(p1 * inv);
  }

  // ================= BIAS MLP =================
  __syncthreads();
  runLayer(IC<8>{}, IC<4>{}, IC<1>{}, getBx);    // L1 x-half (C=0)
  __syncthreads();
  stageW(106496, 32);                            // L1y
  __syncthreads();
  runLayer(IC<8>{}, IC<4>{}, IC<0>{}, getBy);    // L1 y-half
  __syncthreads();
  stageW(122880, 32);                            // H1
  finishLayer(bias_b_in, true);
  __syncthreads();
  runLayer(IC<8>{}, IC<4>{}, IC<1>{}, getBn);    // H1
  __syncthreads();
  stageW(139264, 32);                            // H2
  finishLayer(bias_b_hid + 0, true);
  __syncthreads();
  runLayer(IC<8>{}, IC<4>{}, IC<1>{}, getBn);    // H2
  __syncthreads();
  stageW(155648, 32);                            // H3
  finishLayer(bias_b_hid + 128, true);
  __syncthreads();
  runLayer(IC<8>{}, IC<4>{}, IC<1>{}, getBn);    // H3
  __syncthreads();
  stageW(172032, 8);                             // BIAS OUT (T=1)
  finishLayer(bias_b_hid + 256, true);
  __syncthreads();
  runLayer(IC<8>{}, IC<1>{}, IC<1>{}, getBn);    // BIAS OUT

  // ================= output =================
  // j=0 lives at reg 0 on lower-half lanes (h=0)
  if (lane < 32) {
    float bi = acc[0][0] + bias_b_out[0];
    int off = e & (NK - 1);
    float g0 = ga[((size_t)b << 20) + off];
    float g1 = ga[((size_t)b << 20) + NK + off];
    out[e] = a0v * (g0 - bi) + a1v * (g1 - bi);
  }
}

extern "C" void kernel_launch(void* const* d_in, const int* in_sizes, int n_in,
                              void* d_out, int out_size, void* d_ws, size_t ws_size,
                              hipStream_t stream) {
  const float* backbone   = (const float*)d_in[0];
  const float* ga         = (const float*)d_in[1];
  const float* embed      = (const float*)d_in[2];
  const float* enc_w_in   = (const float*)d_in[3];
  const float* enc_b_in   = (const float*)d_in[4];
  const float* enc_w_hid  = (const float*)d_in[5];
  const float* enc_b_hid  = (const float*)d_in[6];
  const float* enc_w_out  = (const float*)d_in[7];
  const float* enc_b_out  = (const float*)d_in[8];
  const float* bias_w_in  = (const float*)d_in[9];
  const float* bias_b_in  = (const float*)d_in[10];
  const float* bias_w_hid = (const float*)d_in[11];
  const float* bias_b_hid = (const float*)d_in[12];
  const float* bias_w_out = (const float*)d_in[13];
  const float* bias_b_out = (const float*)d_in[14];
  const int*   indices    = (const int*)d_in[15];

  u16*   wpk  = (u16*)d_ws;
  float* embn = (float*)((char*)d_ws + EMBN_OFF);
  u16*   bb16 = (u16*)((char*)d_ws + BB16_OFF);

  hipLaunchKernelGGL(prep_kernel, dim3(689), dim3(256), 0, stream,
                     enc_w_in, enc_w_hid, enc_w_out,
                     bias_w_in, bias_w_hid, bias_w_out,
                     embed, wpk, embn);

  bool bf = (ws_size >= (size_t)WS_NEED);
  if (bf) {
    hipLaunchKernelGGL(prep_backbone, dim3(4096), dim3(256), 0, stream, backbone, bb16);
    hipLaunchKernelGGL((fused_kernel<true>), dim3(8192), dim3(256), 0, stream,
                       backbone, bb16, ga, indices,
                       enc_b_in, enc_b_hid, enc_b_out,
                       bias_b_in, bias_b_hid, bias_b_out,
                       wpk, embn, (float*)d_out);
  } else {
    hipLaunchKernelGGL((fused_kernel<false>), dim3(8192), dim3(256), 0, stream,
                       backbone, bb16, ga, indices,
                       enc_b_in, enc_b_hid, enc_b_out,
                       bias_b_in, bias_b_hid, bias_b_out,
                       wpk, embn, (float*)d_out);
  }
}

// Round 8
// 592.397 us; speedup vs baseline: 1.9315x; 1.0341x over previous
//
#include <hip/hip_runtime.h>

typedef short frag   __attribute__((ext_vector_type(8)));
typedef float f32x4  __attribute__((ext_vector_type(4)));
typedef float f32x16 __attribute__((ext_vector_type(16)));
typedef unsigned short u16;

#define E_TOT 1048576   // B*N*K
#define NK    524288    // N*K

// ws layout (bytes): wpk [0,352256); embn [352256,352768); bb16 [352768, +8388608)
#define WPK_US   176128
#define EMBN_OFF 352256
#define BB16_OFF 352768
#define WS_NEED  (BB16_OFF + 8388608)

__device__ __forceinline__ u16 f2bf(float f){
  unsigned int u = __float_as_uint(f);
  u += 0x7FFFu + ((u >> 16) & 1u);          // RNE
  return (u16)(u >> 16);
}
__device__ __forceinline__ unsigned cvtpk(float lo, float hi){
  unsigned r;
  asm("v_cvt_pk_bf16_f32 %0, %1, %2" : "=v"(r) : "v"(lo), "v"(hi));
  return r;
}
// in-place: a = [a_lo, b_lo], b = [a_hi, b_hi]
__device__ __forceinline__ void plswap(unsigned &a, unsigned &b){
  asm("v_permlane32_swap_b32 %0, %1" : "+v"(a), "+v"(b));
}
__device__ __forceinline__ float frcp(float x){ return __builtin_amdgcn_rcpf(x); }
__device__ __forceinline__ float vexp2(float x){
  float r; asm("v_exp_f32 %0, %1" : "=v"(r) : "v"(x)); return r;
}
__device__ __forceinline__ float sigm(float y){
  return frcp(1.f + vexp2(-1.4426950408889634f * y));
}
__device__ __forceinline__ float gelu_f(float x){
  const float C1 = 2.0f * 0.7978845608028654f * 1.4426950408889634f;
  const float C2 = 0.044715f * C1;
  float z = x * fmaf(C2, x * x, C1);
  return x * frcp(1.f + vexp2(-z));
}

__device__ __forceinline__ void gl_lds16(const void* g, void* l){
#if __has_builtin(__builtin_amdgcn_global_load_lds)
  __builtin_amdgcn_global_load_lds(
      (const __attribute__((address_space(1))) unsigned int*)g,
      (__attribute__((address_space(3))) unsigned int*)l, 16, 0, 0);
#else
  *(uint4*)l = *(const uint4*)g;
#endif
}

template<int N> struct IC { static constexpr int value = N; };

// ---------------- prep: pack weights into 32x32x16 A-fragment layout ----------------
// chunk c, frag f = t*8+s, lane, elem e:  element = W[k][j],
//   j = 32t + (lane&31),  k = 16s + 8*(lane>>5) + e + koff[c]
__global__ void prep_kernel(const float* __restrict__ enc_w_in,
                            const float* __restrict__ enc_w_hid,
                            const float* __restrict__ enc_w_out,
                            const float* __restrict__ bias_w_in,
                            const float* __restrict__ bias_w_hid,
                            const float* __restrict__ bias_w_out,
                            const float* __restrict__ embed_table,
                            u16* __restrict__ wpk,
                            float* __restrict__ embn)
{
  int p = blockIdx.x * 256 + threadIdx.x;
  if (p < WPK_US) {
    const int base[12] = {0,16384,32768,49152,65536,81920,90112,106496,122880,139264,155648,172032};
    const int koff[12] = {0,128,0,0,0,0,0,128,0,0,0,0};
    const int njv[12]  = {128,128,128,128,128,64,128,128,128,128,128,1};
    const float* srcs[12] = {enc_w_in, enc_w_in, enc_w_hid, enc_w_hid+16384, enc_w_hid+32768,
                             enc_w_out, bias_w_in, bias_w_in, bias_w_hid, bias_w_hid+16384,
                             bias_w_hid+32768, bias_w_out};
    int L = 0;
    #pragma unroll
    for (int i = 1; i < 12; ++i) if (p >= base[i]) L = i;
    int r    = p - base[L];
    int f    = r >> 9;
    int q    = r & 511;
    int lane = q >> 3, e = q & 7;
    int t    = f >> 3, s = f & 7;
    int nj   = njv[L];
    int j    = 32*t + (lane & 31);
    int k    = 16*s + 8*(lane >> 5) + e + koff[L];
    wpk[p] = (j < nj) ? f2bf(srcs[L][k * nj + j]) : (u16)0;
  } else if (p < WPK_US + 128) {
    int q = p - WPK_US;
    int m = q >> 6;
    const float* row = embed_table + m * 64;
    float ss = 0.f;
    for (int t = 0; t < 64; ++t) { float v = row[t]; ss += v * v; }
    float nrm = fmaxf(sqrtf(ss), 1e-12f);
    embn[q] = row[q & 63] / nrm;
  }
}

// ---------------- prep: backbone f32 -> bf16 cache ----------------
__global__ void prep_backbone(const float* __restrict__ src, u16* __restrict__ dst)
{
  int i = (blockIdx.x * 256 + threadIdx.x) * 4;
  float4 v = *(const float4*)(src + i);
  unsigned lo = cvtpk(v.x, v.y), hi = cvtpk(v.z, v.w);
  *(uint2*)(dst + i) = make_uint2(lo, hi);
}

// ---------------- fused main kernel: ring-3 half-chunk pipeline ----------------
template<bool BF>
__global__ __launch_bounds__(256, 3)
void fused_kernel(const float* __restrict__ backbone,
                  const u16*   __restrict__ bb16,
                  const float* __restrict__ ga,
                  const int*   __restrict__ idx,
                  const float* __restrict__ enc_b_in,
                  const float* __restrict__ enc_b_hid,
                  const float* __restrict__ enc_b_out,
                  const float* __restrict__ bias_b_in,
                  const float* __restrict__ bias_b_hid,
                  const float* __restrict__ bias_b_out,
                  const u16*   __restrict__ wpk,
                  const float* __restrict__ embn,
                  float* __restrict__ out)
{
  __shared__ __align__(16) u16 wbuf[3][8192];   // 3-slot ring, 16KB each

  const int tid  = threadIdx.x;
  const int w    = tid >> 6;
  const int lane = tid & 63;
  const int h    = lane >> 5;          // k-half
  const int col  = lane & 31;          // edge within wave tile
  const int eW   = blockIdx.x * 128 + w * 32;
  const int e    = eW + col;

  // half-chunk table: u16 base offsets; all 16 frags except #21 (8)
  auto stageHalf = [&](int hh){
    const int hb[22] = {0,8192, 16384,24576, 32768,40960, 49152,57344,
                        65536,73728, 81920, 90112,98304, 106496,114688,
                        122880,131072, 139264,147456, 155648,163840, 172032};
    int base = hb[hh];
    int nf   = (hh == 21) ? 8 : 16;
    int slot = hh % 3;
    for (int it = w; it < nf; it += 4)
      gl_lds16((const void*)(wpk + base + it * 512 + lane * 8),
               (void*)(&wbuf[slot][it * 512]));
  };

  // gather row indices
  int b = e >> 19;
  int rxi = (b << 14) + idx[E_TOT + e];
  int ryi = (b << 14) + idx[2 * E_TOT + e];

  f32x16 acc[4];
  unsigned nb[8][4];
  const f32x16 kZ = {0.f,0.f,0.f,0.f, 0.f,0.f,0.f,0.f, 0.f,0.f,0.f,0.f, 0.f,0.f,0.f,0.f};

  union FU { unsigned u[4]; frag f; };

  auto getB_g = [&](int ri, int s) -> frag {
    size_t off = (((size_t)(unsigned)ri) << 7) + 16 * s + 8 * h;
    if constexpr (BF) {
      return *(const frag*)(bb16 + off);
    } else {
      const float* p = backbone + off;
      float4 lo = *(const float4*)p, hi = *(const float4*)(p + 4);
      FU fu;
      fu.u[0] = cvtpk(lo.x, lo.y); fu.u[1] = cvtpk(lo.z, lo.w);
      fu.u[2] = cvtpk(hi.x, hi.y); fu.u[3] = cvtpk(hi.z, hi.w);
      return fu.f;
    }
  };
  auto getBx = [&](int s) -> frag { return getB_g(rxi, s); };
  auto getBy = [&](int s) -> frag { return getB_g(ryi, s); };
  auto getBn = [&](int s) -> frag {
    FU fu;
    fu.u[0] = nb[s][0]; fu.u[1] = nb[s][1];
    fu.u[2] = nb[s][2]; fu.u[3] = nb[s][3];
    return fu.f;
  };

  // compute one half: tiles T0..T0+TN-1 from ring slot; ZF: s==0 uses C=0
  auto runHalf = [&](auto SLOTC, auto T0C, auto TNC, auto ZFC, auto getB){
    constexpr int slot = decltype(SLOTC)::value;
    constexpr int T0   = decltype(T0C)::value;
    constexpr int TN   = decltype(TNC)::value;
    constexpr bool ZF  = (decltype(ZFC)::value != 0);
    __builtin_amdgcn_s_setprio(1);
    #pragma unroll
    for (int s = 0; s < 8; ++s) {
      frag B = getB(s);
      #pragma unroll
      for (int tt = 0; tt < TN; ++tt) {
        frag A = *(const frag*)(&wbuf[slot][(tt * 8 + s) * 512 + lane * 8]);
        if (ZF && s == 0)
          acc[T0 + tt] = __builtin_amdgcn_mfma_f32_32x32x16_bf16(A, B, kZ, 0, 0, 0);
        else
          acc[T0 + tt] = __builtin_amdgcn_mfma_f32_32x32x16_bf16(A, B, acc[T0 + tt], 0, 0, 0);
      }
    }
    __builtin_amdgcn_s_setprio(0);
  };

  // bias + act + permlane transpose into nb (tile t -> k-steps 2t, 2t+1)
  auto finishLayer = [&](const float* bptr, bool gelu){
    #pragma unroll
    for (int t = 0; t < 4; ++t) {
      float x[16];
      #pragma unroll
      for (int q = 0; q < 4; ++q) {
        f32x4 bv = *(const f32x4*)(bptr + 32*t + 8*q + 4*h);
        #pragma unroll
        for (int i = 0; i < 4; ++i) x[4*q+i] = acc[t][4*q+i] + bv[i];
      }
      #pragma unroll
      for (int i = 0; i < 16; ++i)
        x[i] = gelu ? gelu_f(x[i]) : fmaxf(x[i], 0.f);
      unsigned wv[8];
      #pragma unroll
      for (int i = 0; i < 8; ++i) wv[i] = cvtpk(x[2*i], x[2*i+1]);
      plswap(wv[0], wv[2]); plswap(wv[1], wv[3]);
      plswap(wv[4], wv[6]); plswap(wv[5], wv[7]);
      nb[2*t][0] = wv[0]; nb[2*t][1] = wv[1]; nb[2*t][2] = wv[2]; nb[2*t][3] = wv[3];
      nb[2*t+1][0] = wv[4]; nb[2*t+1][1] = wv[5]; nb[2*t+1][2] = wv[6]; nb[2*t+1][3] = wv[7];
    }
  };

  // ---------------- prologue: stage halves 0,1 ----------------
  stageHalf(0); stageHalf(1);
  __syncthreads();

  // ================= ENC MLP =================
  // phase i: stage half i+2, compute half i, [finish], barrier
  stageHalf(2);  runHalf(IC<0>{}, IC<0>{}, IC<2>{}, IC<1>{}, getBx); __syncthreads();  // 0: L1x t01
  stageHalf(3);  runHalf(IC<1>{}, IC<2>{}, IC<2>{}, IC<1>{}, getBx); __syncthreads();  // 1: L1x t23
  stageHalf(4);  runHalf(IC<2>{}, IC<0>{}, IC<2>{}, IC<0>{}, getBy); __syncthreads();  // 2: L1y t01
  stageHalf(5);  runHalf(IC<0>{}, IC<2>{}, IC<2>{}, IC<0>{}, getBy);                   // 3: L1y t23
  finishLayer(enc_b_in, false); __syncthreads();
  stageHalf(6);  runHalf(IC<1>{}, IC<0>{}, IC<2>{}, IC<1>{}, getBn); __syncthreads();  // 4: H1 t01
  stageHalf(7);  runHalf(IC<2>{}, IC<2>{}, IC<2>{}, IC<1>{}, getBn);                   // 5: H1 t23
  finishLayer(enc_b_hid + 0, false); __syncthreads();
  stageHalf(8);  runHalf(IC<0>{}, IC<0>{}, IC<2>{}, IC<1>{}, getBn); __syncthreads();  // 6: H2 t01
  stageHalf(9);  runHalf(IC<1>{}, IC<2>{}, IC<2>{}, IC<1>{}, getBn);                   // 7: H2 t23
  finishLayer(enc_b_hid + 128, false); __syncthreads();
  stageHalf(10); runHalf(IC<2>{}, IC<0>{}, IC<2>{}, IC<1>{}, getBn); __syncthreads();  // 8: H3 t01
  stageHalf(11); runHalf(IC<0>{}, IC<2>{}, IC<2>{}, IC<1>{}, getBn);                   // 9: H3 t23
  finishLayer(enc_b_hid + 256, false); __syncthreads();
  stageHalf(12); runHalf(IC<1>{}, IC<0>{}, IC<2>{}, IC<1>{}, getBn);                   // 10: ENC OUT (T=2)

  // ---- enc epilogue: bias add, L2-normalize, sigmoid dots ----
  float a0v, a1v;
  {
    float s2 = 0.f, p0 = 0.f, p1 = 0.f;
    #pragma unroll
    for (int t = 0; t < 2; ++t)
      #pragma unroll
      for (int q = 0; q < 4; ++q) {
        f32x4 bv = *(const f32x4*)(enc_b_out + 32*t + 8*q + 4*h);
        f32x4 e0 = *(const f32x4*)(embn + 32*t + 8*q + 4*h);
        f32x4 e1 = *(const f32x4*)(embn + 64 + 32*t + 8*q + 4*h);
        #pragma unroll
        for (int i = 0; i < 4; ++i) {
          float v = acc[t][4*q+i] + bv[i];
          s2 = fmaf(v, v, s2);
          p0 = fmaf(v, e0[i], p0);
          p1 = fmaf(v, e1[i], p1);
        }
      }
    s2 += __shfl_xor(s2, 32);
    p0 += __shfl_xor(p0, 32);
    p1 += __shfl_xor(p1, 32);
    float inv = frcp(fmaxf(sqrtf(s2), 1e-12f));
    a0v = sigm(p0 * inv);
    a1v = sigm(p1 * inv);
  }
  __syncthreads();

  // ================= BIAS MLP =================
  stageHalf(13); runHalf(IC<2>{}, IC<0>{}, IC<2>{}, IC<1>{}, getBx); __syncthreads();  // 11: bL1x t01
  stageHalf(14); runHalf(IC<0>{}, IC<2>{}, IC<2>{}, IC<1>{}, getBx); __syncthreads();  // 12: bL1x t23
  stageHalf(15); runHalf(IC<1>{}, IC<0>{}, IC<2>{}, IC<0>{}, getBy); __syncthreads();  // 13: bL1y t01
  stageHalf(16); runHalf(IC<2>{}, IC<2>{}, IC<2>{}, IC<0>{}, getBy);                   // 14: bL1y t23
  finishLayer(bias_b_in, true); __syncthreads();
  stageHalf(17); runHalf(IC<0>{}, IC<0>{}, IC<2>{}, IC<1>{}, getBn); __syncthreads();  // 15: bH1 t01
  stageHalf(18); runHalf(IC<1>{}, IC<2>{}, IC<2>{}, IC<1>{}, getBn);                   // 16: bH1 t23
  finishLayer(bias_b_in ? bias_b_hid + 0 : bias_b_hid, true); __syncthreads();
  stageHalf(19); runHalf(IC<2>{}, IC<0>{}, IC<2>{}, IC<1>{}, getBn); __syncthreads();  // 17: bH2 t01
  stageHalf(20); runHalf(IC<0>{}, IC<2>{}, IC<2>{}, IC<1>{}, getBn);                   // 18: bH2 t23
  finishLayer(bias_b_hid + 128, true); __syncthreads();
  stageHalf(21); runHalf(IC<1>{}, IC<0>{}, IC<2>{}, IC<1>{}, getBn); __syncthreads();  // 19: bH3 t01
                 runHalf(IC<2>{}, IC<2>{}, IC<2>{}, IC<1>{}, getBn);                   // 20: bH3 t23
  finishLayer(bias_b_hid + 256, true); __syncthreads();
                 runHalf(IC<0>{}, IC<0>{}, IC<1>{}, IC<1>{}, getBn);                   // 21: bOUT (T=1)

  // ================= output =================
  if (lane < 32) {
    float bi = acc[0][0] + bias_b_out[0];
    int off = e & (NK - 1);
    float g0 = ga[((size_t)b << 20) + off];
    float g1 = ga[((size_t)b << 20) + NK + off];
    out[e] = a0v * (g0 - bi) + a1v * (g1 - bi);
  }
}

extern "C" void kernel_launch(void* const* d_in, const int* in_sizes, int n_in,
                              void* d_out, int out_size, void* d_ws, size_t ws_size,
                              hipStream_t stream) {
  const float* backbone   = (const float*)d_in[0];
  const float* ga         = (const float*)d_in[1];
  const float* embed      = (const float*)d_in[2];
  const float* enc_w_in   = (const float*)d_in[3];
  const float* enc_b_in   = (const float*)d_in[4];
  const float* enc_w_hid  = (const float*)d_in[5];
  const float* enc_b_hid  = (const float*)d_in[6];
  const float* enc_w_out  = (const float*)d_in[7];
  const float* enc_b_out  = (const float*)d_in[8];
  const float* bias_w_in  = (const float*)d_in[9];
  const float* bias_b_in  = (const float*)d_in[10];
  const float* bias_w_hid = (const float*)d_in[11];
  const float* bias_b_hid = (const float*)d_in[12];
  const float* bias_w_out = (const float*)d_in[13];
  const float* bias_b_out = (const float*)d_in[14];
  const int*   indices    = (const int*)d_in[15];

  u16*   wpk  = (u16*)d_ws;
  float* embn = (float*)((char*)d_ws + EMBN_OFF);
  u16*   bb16 = (u16*)((char*)d_ws + BB16_OFF);

  hipLaunchKernelGGL(prep_kernel, dim3(689), dim3(256), 0, stream,
                     enc_w_in, enc_w_hid, enc_w_out,
                     bias_w_in, bias_w_hid, bias_w_out,
                     embed, wpk, embn);

  bool bf = (ws_size >= (size_t)WS_NEED);
  if (bf) {
    hipLaunchKernelGGL(prep_backbone, dim3(4096), dim3(256), 0, stream, backbone, bb16);
    hipLaunchKernelGGL((fused_kernel<true>), dim3(8192), dim3(256), 0, stream,
                       backbone, bb16, ga, indices,
                       enc_b_in, enc_b_hid, enc_b_out,
                       bias_b_in, bias_b_hid, bias_b_out,
                       wpk, embn, (float*)d_out);
  } else {
    hipLaunchKernelGGL((fused_kernel<false>), dim3(8192), dim3(256), 0, stream,
                       backbone, bb16, ga, indices,
                       enc_b_in, enc_b_hid, enc_b_out,
                       bias_b_in, bias_b_hid, bias_b_out,
                       wpk, embn, (float*)d_out);
  }
}